// Round 20
// baseline (196.617 us; speedup 1.0000x reference)
//
#include <hip/hip_runtime.h>

typedef unsigned short u16;
typedef __attribute__((ext_vector_type(8))) short short8;
typedef __attribute__((ext_vector_type(4))) float f32x4;
typedef __attribute__((ext_vector_type(4))) unsigned u32x4;

// Problem dims
#define Bq 4
#define Sq 2048
#define Dq 1024
#define Hq 16
#define HDq 64
#define BSq 8192   // B*S

// Q pre-scale: 1/sqrt(64) * log2(e)  (softmax done in exp2 domain)
#define QSCALE 0.18033688011112042f

__device__ __forceinline__ u16 f2bf(float f) {
  unsigned u = __builtin_bit_cast(unsigned, f);
  unsigned r = u + 0x7fffu + ((u >> 16) & 1u);
  return (u16)(r >> 16);
}

// pack two floats -> (bf16(a) | bf16(b)<<16)
__device__ __forceinline__ unsigned pk2(float a, float b) {
  unsigned ua = __builtin_bit_cast(unsigned, a) + 0x8000u;
  unsigned ub = __builtin_bit_cast(unsigned, b) + 0x8000u;
  return __builtin_amdgcn_perm(ub, ua, 0x07060302u);
}

// single-instruction pack: dst = {lo: bf16(a), hi: bf16(b)}
__device__ __forceinline__ unsigned cvtpk(float a, float b) {
  unsigned r;
  asm("v_cvt_pk_bf16_f32 %0, %1, %2" : "=v"(r) : "v"(a), "v"(b));
  return r;
}

// async global->LDS, 16B per lane (dest = wave-uniform base + lane*16)
__device__ __forceinline__ void gl_lds16(const u16* g, u16* l) {
  __builtin_amdgcn_global_load_lds((const __attribute__((address_space(1))) unsigned int*)g,
                                   (__attribute__((address_space(3))) unsigned int*)l, 16, 0, 0);
}

// k-permutation for V^T storage: kk = 16m + 4g + r -> s' = 32(m&1) + 8g + 4(m>>1) + r
__device__ __forceinline__ int kperm(int kk) {
  return ((kk & 0x10) << 1) | ((kk & 0x0C) << 1) | ((kk & 0x20) >> 3) | (kk & 3);
}

// ---------------- fp32 -> bf16 convert (8 floats/thread) ----------------
__global__ void cvt_kernel(const float* __restrict__ in, u16* __restrict__ out, int n8) {
  int i = blockIdx.x * blockDim.x + threadIdx.x;
  if (i >= n8) return;
  float4 v0 = reinterpret_cast<const float4*>(in)[2 * i];
  float4 v1 = reinterpret_cast<const float4*>(in)[2 * i + 1];
  u32x4 o;
  o[0] = pk2(v0.x, v0.y); o[1] = pk2(v0.z, v0.w);
  o[2] = pk2(v1.x, v1.y); o[3] = pk2(v1.z, v1.w);
  reinterpret_cast<u32x4*>(out)[i] = o;
}

// ---------------- transpose + convert: fp32 [R][C] -> bf16 [C][R] ----------------
__global__ void transpose_cvt(const float* __restrict__ in, u16* __restrict__ out, int R, int C) {
  __shared__ float tile[32][33];
  int c0 = blockIdx.x * 32, r0 = blockIdx.y * 32;
  for (int i = threadIdx.y; i < 32; i += 8)
    tile[i][threadIdx.x] = in[(size_t)(r0 + i) * C + c0 + threadIdx.x];
  __syncthreads();
  for (int i = threadIdx.y; i < 32; i += 8)
    out[(size_t)(c0 + i) * R + r0 + threadIdx.x] = f2bf(tile[threadIdx.x][i]);
}

// ---------------- bf16 GEMM: C[M,N] = A[M,K] * Bt[N,K]^T  (+bias) ----------------
// 128^2 tile, 4 waves, BK=64, single-buffered m97-style 2-barrier loop.
// (round-15 proven config: 16 ds_read_b128 feed 32 MFMA per wave per K-step)
// EPI 0: QKV epilogue; EPI 1: proj -> fp32 Out
template<int EPI>
__global__ __launch_bounds__(256)
void gemm_bt(const u16* __restrict__ A, const u16* __restrict__ Bt,
             const float* __restrict__ bias,
             u16* __restrict__ Qb, u16* __restrict__ Kb, u16* __restrict__ Vt,
             float* __restrict__ Out, int Kdim) {
  __shared__ __align__(16) u16 As[128 * 64];   // 16KB
  __shared__ __align__(16) u16 Bs[128 * 64];   // 16KB
  int tid = threadIdx.x;
  int lane = tid & 63;
  int wid = tid >> 6;
  int wr = wid >> 1, wc = wid & 1;       // 2x2 waves; each computes 64x64
  constexpr int NX = (EPI == 0) ? 24 : 8;        // N tiles
  constexpr int NWG = NX * 64;                   // both % 8 == 0
  int orig = (int)blockIdx.x + NX * (int)blockIdx.y;
  int swz = (orig & 7) * (NWG >> 3) + (orig >> 3);
  int m0 = (swz / NX) * 128, n0 = (swz % NX) * 128;
  int l15 = lane & 15, g = lane >> 4;
  f32x4 acc[4][4] = {};

  // staging map: f = i*256+tid (i=0..3); row = f>>3, slot = f&7;
  // LDS[row][slot*8..] holds global chunk (slot ^ (row&7)) -> linear dest f*16B
  const u16* aP[4];
  const u16* bP[4];
#pragma unroll
  for (int i = 0; i < 4; ++i) {
    int f = i * 256 + tid;
    int row = f >> 3, slot = f & 7;
    int src = ((slot ^ (row & 7)) << 3);
    aP[i] = &A[(size_t)(m0 + row) * Kdim + src];
    bP[i] = &Bt[(size_t)(n0 + row) * Kdim + src];
  }

  int nk = Kdim >> 6;   // BK=64
  for (int t = 0; t < nk; ++t) {
    __syncthreads();    // previous step's frag reads complete
    int ko = t << 6;
#pragma unroll
    for (int i = 0; i < 4; ++i) {
      int f = i * 256 + tid;
      gl_lds16(aP[i] + ko, &As[f << 3]);
      gl_lds16(bP[i] + ko, &Bs[f << 3]);
    }
    __syncthreads();    // vmcnt drained -> tiles visible
#pragma unroll
    for (int ksub = 0; ksub < 2; ++ksub) {
      int sl = (((ksub << 2) | g) ^ (l15 & 7)) << 3;
      short8 af[4], bfr[4];
#pragma unroll
      for (int m = 0; m < 4; ++m)
        af[m] = *reinterpret_cast<const short8*>(&As[(wr * 64 + m * 16 + l15) * 64 + sl]);
#pragma unroll
      for (int n = 0; n < 4; ++n)
        bfr[n] = *reinterpret_cast<const short8*>(&Bs[(wc * 64 + n * 16 + l15) * 64 + sl]);
      __builtin_amdgcn_s_setprio(1);
#pragma unroll
      for (int m = 0; m < 4; ++m)
#pragma unroll
        for (int n = 0; n < 4; ++n)
          acc[m][n] = __builtin_amdgcn_mfma_f32_16x16x32_bf16(af[m], bfr[n], acc[m][n], 0, 0, 0);
      __builtin_amdgcn_s_setprio(0);
    }
  }

  int bb = (m0 + wr * 64) >> 11;        // batch (wave-uniform)
  int sb = (m0 + wr * 64) & 2047;       // seq base (64-aligned)

  if (EPI == 1) {
#pragma unroll
    for (int m = 0; m < 4; ++m)
#pragma unroll
      for (int n = 0; n < 4; ++n) {
        int gcol = n0 + wc * 64 + n * 16 + l15;
        float bv = bias[gcol];
#pragma unroll
        for (int r = 0; r < 4; ++r) {
          int grow = m0 + wr * 64 + m * 16 + g * 4 + r;
          Out[(size_t)grow * 1024 + gcol] = acc[m][n][r] + bv;
        }
      }
  } else if (n0 < 1024) {               // Q block (scaled)
#pragma unroll
    for (int n = 0; n < 4; ++n) {
      int col = n0 + wc * 64 + n * 16 + l15;
      int hh = col >> 6, d = col & 63;
      float bv = bias[col];
      u16* qb = &Qb[(((size_t)(bb * 16 + hh) * 2048 + sb) << 6) + d];
#pragma unroll
      for (int m = 0; m < 4; ++m)
#pragma unroll
        for (int r = 0; r < 4; ++r)
          qb[(size_t)(m * 16 + g * 4 + r) << 6] = f2bf((acc[m][n][r] + bv) * QSCALE);
    }
  } else if (n0 < 2048) {               // K block
#pragma unroll
    for (int n = 0; n < 4; ++n) {
      int col = n0 - 1024 + wc * 64 + n * 16 + l15;
      int hh = col >> 6, d = col & 63;
      float bv = bias[1024 + col];
      u16* kb = &Kb[(((size_t)(bb * 16 + hh) * 2048 + sb) << 6) + d];
#pragma unroll
      for (int m = 0; m < 4; ++m)
#pragma unroll
        for (int r = 0; r < 4; ++r)
          kb[(size_t)(m * 16 + g * 4 + r) << 6] = f2bf(acc[m][n][r] + bv);
    }
  } else {                              // V block: vectorized k-permuted transpose write
#pragma unroll
    for (int n = 0; n < 4; ++n) {
      int cc = n0 - 2048 + wc * 64 + n * 16 + l15;
      int hh = cc >> 6, d = cc & 63;
      float bv = bias[2048 + cc];
      u16* dst = &Vt[((size_t)(bb * 16 + hh) * 64 + d) * 2048 + sb];
      u32x4 lo, hi;
      lo[0] = pk2(acc[0][n][0] + bv, acc[0][n][1] + bv);
      lo[1] = pk2(acc[0][n][2] + bv, acc[0][n][3] + bv);
      lo[2] = pk2(acc[2][n][0] + bv, acc[2][n][1] + bv);
      lo[3] = pk2(acc[2][n][2] + bv, acc[2][n][3] + bv);
      hi[0] = pk2(acc[1][n][0] + bv, acc[1][n][1] + bv);
      hi[1] = pk2(acc[1][n][2] + bv, acc[1][n][3] + bv);
      hi[2] = pk2(acc[3][n][0] + bv, acc[3][n][1] + bv);
      hi[3] = pk2(acc[3][n][2] + bv, acc[3][n][3] + bv);
      *reinterpret_cast<u32x4*>(dst + g * 8) = lo;
      *reinterpret_cast<u32x4*>(dst + 32 + g * 8) = hi;
    }
  }
}

// ---------------- flash attention (causal), swapped-QK^T, LDS-staged K/V ----------------
// grid: (16, 64) = 1024 blocks, 128 threads (2 waves), XCD-locality remap.
// Block does q-tile pair (31-bx, bx): 33 k-blocks of 64 processed as 17 DOUBLE
// steps (KVBLK=128): single 32KB buffer, 2 barriers per double step -> per-block
// iteration overhead (stage drain + chain warmup) halves vs dbuf-64.
// Wave owns 32 rows (2 subtiles of 16) sharing each K/V read set.
// FIXED-max softmax (P = exp2(s)); row-sum via ones B-frag on the MFMA pipe.
__global__ __launch_bounds__(128, 2)
void attn_kernel(const u16* __restrict__ Qb, const u16* __restrict__ Kb,
                 const u16* __restrict__ Vt, u16* __restrict__ Ctx) {
  __shared__ __align__(16) u16 ldsK[16][512];   // 16KB: half h -> slots 8h..8h+7
  __shared__ __align__(16) u16 ldsV[16][512];   // 16KB
  int tid = threadIdx.x, lane = tid & 63, w = tid >> 6;   // w in {0,1}
  int l15 = lane & 15, g = lane >> 4;
  // XCD-aware remap (dispatch round-robins id%8 across XCDs):
  int id = (int)blockIdx.x + 16 * (int)blockIdx.y;
  int xcd = id & 7, slotid = id >> 3;         // slotid: 0..127 within XCD
  int bh = (xcd << 3) | (slotid >> 4);        // 8 bh per XCD, 16 blocks each
  int bx = slotid & 15;                       // tile-pair index within bh
  const u16* Qh = Qb + (size_t)bh * Sq * HDq;
  const u16* Kh = Kb + (size_t)bh * Sq * HDq;
  const u16* Vh = Vt + (size_t)bh * HDq * Sq;
  int b = bh >> 4, h = bh & 15;

  int tileA = 31 - bx, tileB = bx;
  int nkA = tileA + 1;
  int ntot = nkA + tileB + 1;   // == 33 for every block

  // wave-lane-resolved staging bases (wave w: k/d rows 32w..32w+31)
  const u16* ksrc = Kh + (size_t)(32 * w + l15) * 64 + 8 * g;
  const u16* vsrc = Vh + (size_t)(32 * w + l15) * Sq + 8 * g;

  int qrow = tileA * 64 + 32 * w;   // wave's rows: [qrow, qrow+32)

  short8 qf[2][2];
#pragma unroll
  for (int s = 0; s < 2; ++s)
#pragma unroll
    for (int hh = 0; hh < 2; ++hh)
      qf[s][hh] = *reinterpret_cast<const short8*>(&Qh[(size_t)(qrow + 16 * s + l15) * 64 + 32 * hh + 8 * g]);

  // ones B-frag: output col 0 of PV-ones = row sum of P
  u16 onebits = (l15 == 0) ? (u16)0x3F80 : (u16)0;
  short8 vones;
#pragma unroll
  for (int i = 0; i < 8; ++i) vones[i] = (short)onebits;

  f32x4 acc[2][4] = {};
  f32x4 acc_l[2] = {};

#pragma unroll 1
  for (int dt = 0; dt < 17; ++dt) {
    __syncthreads();   // previous step's LDS reads complete before overwrite

    // ---- stage phase: both halves (KVBLK=128) ----
#pragma unroll
    for (int hf2 = 0; hf2 < 2; ++hf2) {
      int ith = 2 * dt + hf2;
      if (ith < ntot) {
        int kb = (ith < nkA) ? ith : ith - nkA;
        const u16* kp = ksrc + ((size_t)kb << 12);   // kb*64 rows * 64 cols
        const u16* vp = vsrc + (kb << 6);            // kb*64 col offset
        int sb8 = 8 * hf2 + 4 * w;
        gl_lds16(kp,         &ldsK[sb8][0]);
        gl_lds16(kp + 32,    &ldsK[sb8 + 1][0]);
        gl_lds16(kp + 1024,  &ldsK[sb8 + 2][0]);
        gl_lds16(kp + 1056,  &ldsK[sb8 + 3][0]);
        gl_lds16(vp,         &ldsV[sb8][0]);
        gl_lds16(vp + 32,    &ldsV[sb8 + 1][0]);
        gl_lds16(vp + 32768, &ldsV[sb8 + 2][0]);
        gl_lds16(vp + 32800, &ldsV[sb8 + 3][0]);
      }
    }
    __syncthreads();   // vmcnt drained -> both halves visible

    // ---- compute phase: both halves ----
#pragma unroll
    for (int hf2 = 0; hf2 < 2; ++hf2) {
      int ith = 2 * dt + hf2;
      if (ith >= ntot) continue;
      int kb = (ith < nkA) ? ith : ith - nkA;
      int tcur = (ith < nkA) ? tileA : tileB;
      int k0 = kb << 6;
      int base = 8 * hf2;

      short8 kf[4][2], vbf[4][2];
#pragma unroll
      for (int j = 0; j < 4; ++j) {
        kf[j][0] = *reinterpret_cast<const short8*>(&ldsK[base + 2 * j][lane * 8]);
        kf[j][1] = *reinterpret_cast<const short8*>(&ldsK[base + 2 * j + 1][lane * 8]);
      }
#pragma unroll
      for (int n = 0; n < 4; ++n) {
        vbf[n][0] = *reinterpret_cast<const short8*>(&ldsV[base + 2 * n][lane * 8]);
        vbf[n][1] = *reinterpret_cast<const short8*>(&ldsV[base + 2 * n + 1][lane * 8]);
      }

#pragma unroll
      for (int s = 0; s < 2; ++s) {      // two 16-row subtiles share kf/vbf
        int q0s = qrow + 16 * s;

        f32x4 sj[4];
        __builtin_amdgcn_s_setprio(1);
#pragma unroll
        for (int j = 0; j < 4; ++j) {
          f32x4 z = {};
          z = __builtin_amdgcn_mfma_f32_16x16x32_bf16(kf[j][0], qf[s][0], z, 0, 0, 0);
          z = __builtin_amdgcn_mfma_f32_16x16x32_bf16(kf[j][1], qf[s][1], z, 0, 0, 0);
          sj[j] = z;
        }
        __builtin_amdgcn_s_setprio(0);

        if (kb == tcur) {   // diagonal block: causal mask
          int q = q0s + l15;
#pragma unroll
          for (int j = 0; j < 4; ++j)
#pragma unroll
            for (int r = 0; r < 4; ++r)
              if (k0 + 16 * j + 4 * g + r > q) sj[j][r] = -1e30f;
        }

        // fixed-max softmax: P = exp2(s) directly (masked -> 0)
        float p[4][4];
#pragma unroll
        for (int j = 0; j < 4; ++j)
#pragma unroll
          for (int r = 0; r < 4; ++r)
            p[j][r] = exp2f(sj[j][r]);

        u32x4 w0, w1;
        w0[0] = cvtpk(p[0][0], p[0][1]); w0[1] = cvtpk(p[0][2], p[0][3]);
        w0[2] = cvtpk(p[2][0], p[2][1]); w0[3] = cvtpk(p[2][2], p[2][3]);
        w1[0] = cvtpk(p[1][0], p[1][1]); w1[1] = cvtpk(p[1][2], p[1][3]);
        w1[2] = cvtpk(p[3][0], p[3][1]); w1[3] = cvtpk(p[3][2], p[3][3]);
        short8 pa0 = __builtin_bit_cast(short8, w0);
        short8 pa1 = __builtin_bit_cast(short8, w1);
        __builtin_amdgcn_s_setprio(1);
#pragma unroll
        for (int n = 0; n < 4; ++n) {
          acc[s][n] = __builtin_amdgcn_mfma_f32_16x16x32_bf16(pa0, vbf[n][0], acc[s][n], 0, 0, 0);
          acc[s][n] = __builtin_amdgcn_mfma_f32_16x16x32_bf16(pa1, vbf[n][1], acc[s][n], 0, 0, 0);
        }
        acc_l[s] = __builtin_amdgcn_mfma_f32_16x16x32_bf16(pa0, vones, acc_l[s], 0, 0, 0);
        acc_l[s] = __builtin_amdgcn_mfma_f32_16x16x32_bf16(pa1, vones, acc_l[s], 0, 0, 0);
        __builtin_amdgcn_s_setprio(0);
      }

      if (ith == nkA - 1) {   // tile A done: write out, reset, switch to tile B
#pragma unroll
        for (int s = 0; s < 2; ++s) {
          float lf[4];
#pragma unroll
          for (int r = 0; r < 4; ++r) lf[r] = __shfl(acc_l[s][r], 16 * g);
#pragma unroll
          for (int r = 0; r < 4; ++r) {
            float inv = 1.0f / lf[r];
            int row = qrow + 16 * s + 4 * g + r;
            size_t obase = ((size_t)(b * Sq + row)) * Dq + h * 64;
#pragma unroll
            for (int n = 0; n < 4; ++n)
              Ctx[obase + 16 * n + l15] = f2bf(acc[s][n][r] * inv);
          }
        }
        qrow = tileB * 64 + 32 * w;
#pragma unroll
        for (int s = 0; s < 2; ++s) {
#pragma unroll
          for (int hh = 0; hh < 2; ++hh)
            qf[s][hh] = *reinterpret_cast<const short8*>(&Qh[(size_t)(qrow + 16 * s + l15) * 64 + 32 * hh + 8 * g]);
#pragma unroll
          for (int n = 0; n < 4; ++n) acc[s][n] = f32x4{};
          acc_l[s] = f32x4{};
        }
      }
    }
  }

  {   // tile B epilogue
#pragma unroll
    for (int s = 0; s < 2; ++s) {
      float lf[4];
#pragma unroll
      for (int r = 0; r < 4; ++r) lf[r] = __shfl(acc_l[s][r], 16 * g);
#pragma unroll
      for (int r = 0; r < 4; ++r) {
        float inv = 1.0f / lf[r];
        int row = qrow + 16 * s + 4 * g + r;
        size_t obase = ((size_t)(b * Sq + row)) * Dq + h * 64;
#pragma unroll
        for (int n = 0; n < 4; ++n)
          Ctx[obase + 16 * n + l15] = f2bf(acc[s][n][r] * inv);
      }
    }
  }
}

extern "C" void kernel_launch(void* const* d_in, const int* in_sizes, int n_in,
                              void* d_out, int out_size, void* d_ws, size_t ws_size,
                              hipStream_t stream) {
  const float* X  = (const float*)d_in[0];   // [B,S,D] fp32
  const float* Wa = (const float*)d_in[1];   // [D,3D]
  const float* Ba = (const float*)d_in[2];   // [3D]
  const float* Wp = (const float*)d_in[3];   // [D,D]
  const float* Bp = (const float*)d_in[4];   // [D]
  float* Out = (float*)d_out;                // [B,S,D] fp32

  u16* ws  = (u16*)d_ws;
  u16* Xb  = ws;                                 // 8192*1024
  u16* WaT = Xb  + (size_t)BSq * Dq;             // 3072*1024
  u16* WpT = WaT + (size_t)3 * Dq * Dq;          // 1024*1024
  u16* Qb  = WpT + (size_t)Dq * Dq;              // 64*2048*64
  u16* Kb  = Qb  + (size_t)Bq * Hq * Sq * HDq;
  u16* Vt  = Kb  + (size_t)Bq * Hq * Sq * HDq;
  u16* Ctx = Vt  + (size_t)Bq * Hq * Sq * HDq;   // 8192*1024

  // 1) convert X to bf16 (8 floats/thread)
  cvt_kernel<<<(BSq * Dq / 8 + 255) / 256, 256, 0, stream>>>(X, Xb, BSq * Dq / 8);
  // 2) transpose+convert weights: W[K][N] -> WT[N][K] bf16
  transpose_cvt<<<dim3(3 * Dq / 32, Dq / 32), dim3(32, 8), 0, stream>>>(Wa, WaT, Dq, 3 * Dq);
  transpose_cvt<<<dim3(Dq / 32, Dq / 32), dim3(32, 8), 0, stream>>>(Wp, WpT, Dq, Dq);
  // 3) QKV GEMM (M=8192, N=3072, K=1024, BK=64) with Q/K/V scatter epilogue
  gemm_bt<0><<<dim3(3 * Dq / 128, BSq / 128), 256, 0, stream>>>(Xb, WaT, Ba, Qb, Kb, Vt, nullptr, Dq);
  // 4) causal flash attention -> Ctx (XCD remap, paired tiles, KVBLK=128 double steps)
  attn_kernel<<<dim3(16, Bq * Hq), 128, 0, stream>>>(Qb, Kb, Vt, Ctx);
  // 5) output projection (M=8192, N=1024, K=1024, BK=64) -> fp32 out
  gemm_bt<1><<<dim3(Dq / 128, BSq / 128), 256, 0, stream>>>(Ctx, WpT, Bp, nullptr, nullptr, nullptr, Out, Dq);
}

// Round 21
// 176.322 us; speedup vs baseline: 1.1151x; 1.1151x over previous
//
#include <hip/hip_runtime.h>

typedef unsigned short u16;
typedef __attribute__((ext_vector_type(8))) short short8;
typedef __attribute__((ext_vector_type(4))) float f32x4;
typedef __attribute__((ext_vector_type(4))) unsigned u32x4;

// Problem dims
#define Bq 4
#define Sq 2048
#define Dq 1024
#define Hq 16
#define HDq 64
#define BSq 8192   // B*S

// Q pre-scale: 1/sqrt(64) * log2(e)  (softmax done in exp2 domain)
#define QSCALE 0.18033688011112042f

__device__ __forceinline__ u16 f2bf(float f) {
  unsigned u = __builtin_bit_cast(unsigned, f);
  unsigned r = u + 0x7fffu + ((u >> 16) & 1u);
  return (u16)(r >> 16);
}

// pack two floats -> (bf16(a) | bf16(b)<<16)
__device__ __forceinline__ unsigned pk2(float a, float b) {
  unsigned ua = __builtin_bit_cast(unsigned, a) + 0x8000u;
  unsigned ub = __builtin_bit_cast(unsigned, b) + 0x8000u;
  return __builtin_amdgcn_perm(ub, ua, 0x07060302u);
}

// single-instruction pack: dst = {lo: bf16(a), hi: bf16(b)}
__device__ __forceinline__ unsigned cvtpk(float a, float b) {
  unsigned r;
  asm("v_cvt_pk_bf16_f32 %0, %1, %2" : "=v"(r) : "v"(a), "v"(b));
  return r;
}

// async global->LDS, 16B per lane (dest = wave-uniform base + lane*16)
__device__ __forceinline__ void gl_lds16(const u16* g, u16* l) {
  __builtin_amdgcn_global_load_lds((const __attribute__((address_space(1))) unsigned int*)g,
                                   (__attribute__((address_space(3))) unsigned int*)l, 16, 0, 0);
}

// k-permutation for V^T storage: kk = 16m + 4g + r -> s' = 32(m&1) + 8g + 4(m>>1) + r
__device__ __forceinline__ int kperm(int kk) {
  return ((kk & 0x10) << 1) | ((kk & 0x0C) << 1) | ((kk & 0x20) >> 3) | (kk & 3);
}

// ---------------- fp32 -> bf16 convert (8 floats/thread) ----------------
__global__ void cvt_kernel(const float* __restrict__ in, u16* __restrict__ out, int n8) {
  int i = blockIdx.x * blockDim.x + threadIdx.x;
  if (i >= n8) return;
  float4 v0 = reinterpret_cast<const float4*>(in)[2 * i];
  float4 v1 = reinterpret_cast<const float4*>(in)[2 * i + 1];
  u32x4 o;
  o[0] = pk2(v0.x, v0.y); o[1] = pk2(v0.z, v0.w);
  o[2] = pk2(v1.x, v1.y); o[3] = pk2(v1.z, v1.w);
  reinterpret_cast<u32x4*>(out)[i] = o;
}

// ---------------- transpose + convert: fp32 [R][C] -> bf16 [C][R] ----------------
__global__ void transpose_cvt(const float* __restrict__ in, u16* __restrict__ out, int R, int C) {
  __shared__ float tile[32][33];
  int c0 = blockIdx.x * 32, r0 = blockIdx.y * 32;
  for (int i = threadIdx.y; i < 32; i += 8)
    tile[i][threadIdx.x] = in[(size_t)(r0 + i) * C + c0 + threadIdx.x];
  __syncthreads();
  for (int i = threadIdx.y; i < 32; i += 8)
    out[(size_t)(c0 + i) * R + r0 + threadIdx.x] = f2bf(tile[threadIdx.x][i]);
}

// ---------------- bf16 GEMM: C[M,N] = A[M,K] * Bt[N,K]^T  (+bias) ----------------
// 128^2 tile, 4 waves, BK=64, single-buffered m97-style 2-barrier loop.
// (round-15 proven config: 16 ds_read_b128 feed 32 MFMA per wave per K-step)
// EPI 0: QKV epilogue; EPI 1: proj -> fp32 Out
template<int EPI>
__global__ __launch_bounds__(256)
void gemm_bt(const u16* __restrict__ A, const u16* __restrict__ Bt,
             const float* __restrict__ bias,
             u16* __restrict__ Qb, u16* __restrict__ Kb, u16* __restrict__ Vt,
             float* __restrict__ Out, int Kdim) {
  __shared__ __align__(16) u16 As[128 * 64];   // 16KB
  __shared__ __align__(16) u16 Bs[128 * 64];   // 16KB
  int tid = threadIdx.x;
  int lane = tid & 63;
  int wid = tid >> 6;
  int wr = wid >> 1, wc = wid & 1;       // 2x2 waves; each computes 64x64
  constexpr int NX = (EPI == 0) ? 24 : 8;        // N tiles
  constexpr int NWG = NX * 64;                   // both % 8 == 0
  int orig = (int)blockIdx.x + NX * (int)blockIdx.y;
  int swz = (orig & 7) * (NWG >> 3) + (orig >> 3);
  int m0 = (swz / NX) * 128, n0 = (swz % NX) * 128;
  int l15 = lane & 15, g = lane >> 4;
  f32x4 acc[4][4] = {};

  // staging map: f = i*256+tid (i=0..3); row = f>>3, slot = f&7;
  // LDS[row][slot*8..] holds global chunk (slot ^ (row&7)) -> linear dest f*16B
  const u16* aP[4];
  const u16* bP[4];
#pragma unroll
  for (int i = 0; i < 4; ++i) {
    int f = i * 256 + tid;
    int row = f >> 3, slot = f & 7;
    int src = ((slot ^ (row & 7)) << 3);
    aP[i] = &A[(size_t)(m0 + row) * Kdim + src];
    bP[i] = &Bt[(size_t)(n0 + row) * Kdim + src];
  }

  int nk = Kdim >> 6;   // BK=64
  for (int t = 0; t < nk; ++t) {
    __syncthreads();    // previous step's frag reads complete
    int ko = t << 6;
#pragma unroll
    for (int i = 0; i < 4; ++i) {
      int f = i * 256 + tid;
      gl_lds16(aP[i] + ko, &As[f << 3]);
      gl_lds16(bP[i] + ko, &Bs[f << 3]);
    }
    __syncthreads();    // vmcnt drained -> tiles visible
#pragma unroll
    for (int ksub = 0; ksub < 2; ++ksub) {
      int sl = (((ksub << 2) | g) ^ (l15 & 7)) << 3;
      short8 af[4], bfr[4];
#pragma unroll
      for (int m = 0; m < 4; ++m)
        af[m] = *reinterpret_cast<const short8*>(&As[(wr * 64 + m * 16 + l15) * 64 + sl]);
#pragma unroll
      for (int n = 0; n < 4; ++n)
        bfr[n] = *reinterpret_cast<const short8*>(&Bs[(wc * 64 + n * 16 + l15) * 64 + sl]);
      __builtin_amdgcn_s_setprio(1);
#pragma unroll
      for (int m = 0; m < 4; ++m)
#pragma unroll
        for (int n = 0; n < 4; ++n)
          acc[m][n] = __builtin_amdgcn_mfma_f32_16x16x32_bf16(af[m], bfr[n], acc[m][n], 0, 0, 0);
      __builtin_amdgcn_s_setprio(0);
    }
  }

  int bb = (m0 + wr * 64) >> 11;        // batch (wave-uniform)
  int sb = (m0 + wr * 64) & 2047;       // seq base (64-aligned)

  if (EPI == 1) {
#pragma unroll
    for (int m = 0; m < 4; ++m)
#pragma unroll
      for (int n = 0; n < 4; ++n) {
        int gcol = n0 + wc * 64 + n * 16 + l15;
        float bv = bias[gcol];
#pragma unroll
        for (int r = 0; r < 4; ++r) {
          int grow = m0 + wr * 64 + m * 16 + g * 4 + r;
          Out[(size_t)grow * 1024 + gcol] = acc[m][n][r] + bv;
        }
      }
  } else if (n0 < 1024) {               // Q block (scaled)
#pragma unroll
    for (int n = 0; n < 4; ++n) {
      int col = n0 + wc * 64 + n * 16 + l15;
      int hh = col >> 6, d = col & 63;
      float bv = bias[col];
      u16* qb = &Qb[(((size_t)(bb * 16 + hh) * 2048 + sb) << 6) + d];
#pragma unroll
      for (int m = 0; m < 4; ++m)
#pragma unroll
        for (int r = 0; r < 4; ++r)
          qb[(size_t)(m * 16 + g * 4 + r) << 6] = f2bf((acc[m][n][r] + bv) * QSCALE);
    }
  } else if (n0 < 2048) {               // K block
#pragma unroll
    for (int n = 0; n < 4; ++n) {
      int col = n0 - 1024 + wc * 64 + n * 16 + l15;
      int hh = col >> 6, d = col & 63;
      float bv = bias[1024 + col];
      u16* kb = &Kb[(((size_t)(bb * 16 + hh) * 2048 + sb) << 6) + d];
#pragma unroll
      for (int m = 0; m < 4; ++m)
#pragma unroll
        for (int r = 0; r < 4; ++r)
          kb[(size_t)(m * 16 + g * 4 + r) << 6] = f2bf(acc[m][n][r] + bv);
    }
  } else {                              // V block: vectorized k-permuted transpose write
#pragma unroll
    for (int n = 0; n < 4; ++n) {
      int cc = n0 - 2048 + wc * 64 + n * 16 + l15;
      int hh = cc >> 6, d = cc & 63;
      float bv = bias[2048 + cc];
      u16* dst = &Vt[((size_t)(bb * 16 + hh) * 64 + d) * 2048 + sb];
      u32x4 lo, hi;
      lo[0] = pk2(acc[0][n][0] + bv, acc[0][n][1] + bv);
      lo[1] = pk2(acc[0][n][2] + bv, acc[0][n][3] + bv);
      lo[2] = pk2(acc[2][n][0] + bv, acc[2][n][1] + bv);
      lo[3] = pk2(acc[2][n][2] + bv, acc[2][n][3] + bv);
      hi[0] = pk2(acc[1][n][0] + bv, acc[1][n][1] + bv);
      hi[1] = pk2(acc[1][n][2] + bv, acc[1][n][3] + bv);
      hi[2] = pk2(acc[3][n][0] + bv, acc[3][n][1] + bv);
      hi[3] = pk2(acc[3][n][2] + bv, acc[3][n][3] + bv);
      *reinterpret_cast<u32x4*>(dst + g * 8) = lo;
      *reinterpret_cast<u32x4*>(dst + 32 + g * 8) = hi;
    }
  }
}

// ---------------- flash attention (causal), swapped-QK^T, LDS-staged K/V ----------------
// grid: (16, 64) = 1024 blocks, 128 threads (2 waves). XCD-aware remap: each XCD
// runs 16 consecutive same-bh blocks -> K/V panel (512KB) is L2-resident per XCD.
// Block does q-tile pair (31-bx, bx): uniform 33 iters. Wave owns 32 rows (2
// subtiles of 16) sharing each K/V read set. dbuf-2 LDS, 1 barrier/iter.
// FIXED-max softmax; ones-MFMA row-sum.  (round-19 proven config: 176.4 us total)
__global__ __launch_bounds__(128, 2)
void attn_kernel(const u16* __restrict__ Qb, const u16* __restrict__ Kb,
                 const u16* __restrict__ Vt, u16* __restrict__ Ctx) {
  __shared__ __align__(16) u16 lds[2][2][8][512];   // [dbuf][K|V][slot][1KB]
  int tid = threadIdx.x, lane = tid & 63, w = tid >> 6;   // w in {0,1}
  int l15 = lane & 15, g = lane >> 4;
  // XCD-aware remap (dispatch round-robins id%8 across XCDs):
  int id = (int)blockIdx.x + 16 * (int)blockIdx.y;
  int xcd = id & 7, slot = id >> 3;           // slot: 0..127 within XCD
  int bh = (xcd << 3) | (slot >> 4);          // 8 bh per XCD, 16 blocks each
  int bx = slot & 15;                         // tile-pair index within bh
  const u16* Qh = Qb + (size_t)bh * Sq * HDq;
  const u16* Kh = Kb + (size_t)bh * Sq * HDq;
  const u16* Vh = Vt + (size_t)bh * HDq * Sq;
  int b = bh >> 4, h = bh & 15;

  int tileA = 31 - bx, tileB = bx;
  int nkA = tileA + 1;
  int ntot = nkA + tileB + 1;   // == 33 for every block

  // wave w stages K slots {4w..4w+3} (k-rows 32w..32w+31) and V slots {4w..4w+3}
  const u16* ksrc = Kh + (size_t)(32 * w + l15) * 64 + 8 * g;
  const u16* vsrc = Vh + (size_t)(32 * w + l15) * Sq + 8 * g;
  const u16* kpre = ksrc + 4096;   // next prefetch source (kb=1)
  const u16* vpre = vsrc + 64;

  int tile = tileA;
  int qrow = tileA * 64 + 32 * w;   // wave's rows: [qrow, qrow+32)

  short8 qf[2][2];
#pragma unroll
  for (int s = 0; s < 2; ++s)
#pragma unroll
    for (int hh = 0; hh < 2; ++hh)
      qf[s][hh] = *reinterpret_cast<const short8*>(&Qh[(size_t)(qrow + 16 * s + l15) * 64 + 32 * hh + 8 * g]);

  // ones B-frag: output col 0 of PV-ones = row sum of P
  u16 onebits = (l15 == 0) ? (u16)0x3F80 : (u16)0;
  short8 vones;
#pragma unroll
  for (int i = 0; i < 8; ++i) vones[i] = (short)onebits;

  f32x4 acc[2][4] = {};
  f32x4 acc_l[2] = {};

  // prologue: stage iter 0 into buf 0 (wave w: K slots 4w..4w+3, V slots 4w..4w+3)
  gl_lds16(ksrc,         &lds[0][0][4 * w][0]);
  gl_lds16(ksrc + 32,    &lds[0][0][4 * w + 1][0]);
  gl_lds16(ksrc + 1024,  &lds[0][0][4 * w + 2][0]);
  gl_lds16(ksrc + 1056,  &lds[0][0][4 * w + 3][0]);
  gl_lds16(vsrc,         &lds[0][1][4 * w][0]);
  gl_lds16(vsrc + 32,    &lds[0][1][4 * w + 1][0]);
  gl_lds16(vsrc + 32768, &lds[0][1][4 * w + 2][0]);
  gl_lds16(vsrc + 32800, &lds[0][1][4 * w + 3][0]);
  __syncthreads();
  int cur = 0;
  int kb = 0;

#pragma unroll 1
  for (int it = 0; it < ntot; ++it) {
    bool lastA = (it == nkA - 1);
    int k0 = kb << 6;

    if (it + 1 < ntot) {   // prefetch next iteration (strength-reduced pointers)
      gl_lds16(kpre,         &lds[cur ^ 1][0][4 * w][0]);
      gl_lds16(kpre + 32,    &lds[cur ^ 1][0][4 * w + 1][0]);
      gl_lds16(kpre + 1024,  &lds[cur ^ 1][0][4 * w + 2][0]);
      gl_lds16(kpre + 1056,  &lds[cur ^ 1][0][4 * w + 3][0]);
      gl_lds16(vpre,         &lds[cur ^ 1][1][4 * w][0]);
      gl_lds16(vpre + 32,    &lds[cur ^ 1][1][4 * w + 1][0]);
      gl_lds16(vpre + 32768, &lds[cur ^ 1][1][4 * w + 2][0]);
      gl_lds16(vpre + 32800, &lds[cur ^ 1][1][4 * w + 3][0]);
      if (it == nkA - 2) { kpre = ksrc; vpre = vsrc; }   // wrap to tile-B's kb=0
      else               { kpre += 4096; vpre += 64; }
    }

    short8 kf[4][2], vbf[4][2];
#pragma unroll
    for (int j = 0; j < 4; ++j) {
      kf[j][0] = *reinterpret_cast<const short8*>(&lds[cur][0][2 * j][lane * 8]);
      kf[j][1] = *reinterpret_cast<const short8*>(&lds[cur][0][2 * j + 1][lane * 8]);
    }
#pragma unroll
    for (int n = 0; n < 4; ++n) {
      vbf[n][0] = *reinterpret_cast<const short8*>(&lds[cur][1][2 * n][lane * 8]);
      vbf[n][1] = *reinterpret_cast<const short8*>(&lds[cur][1][2 * n + 1][lane * 8]);
    }

#pragma unroll
    for (int s = 0; s < 2; ++s) {      // two 16-row subtiles share kf/vbf
      int q0s = qrow + 16 * s;

      f32x4 sj[4];
      __builtin_amdgcn_s_setprio(1);
#pragma unroll
      for (int j = 0; j < 4; ++j) {
        f32x4 z = {};
        z = __builtin_amdgcn_mfma_f32_16x16x32_bf16(kf[j][0], qf[s][0], z, 0, 0, 0);
        z = __builtin_amdgcn_mfma_f32_16x16x32_bf16(kf[j][1], qf[s][1], z, 0, 0, 0);
        sj[j] = z;
      }
      __builtin_amdgcn_s_setprio(0);

      if (kb == tile) {   // diagonal block: causal mask
        int q = q0s + l15;
#pragma unroll
        for (int j = 0; j < 4; ++j)
#pragma unroll
          for (int r = 0; r < 4; ++r)
            if (k0 + 16 * j + 4 * g + r > q) sj[j][r] = -1e30f;
      }

      // fixed-max softmax: P = exp2(s) directly (masked -> 0)
      float p[4][4];
#pragma unroll
      for (int j = 0; j < 4; ++j)
#pragma unroll
        for (int r = 0; r < 4; ++r)
          p[j][r] = exp2f(sj[j][r]);

      u32x4 w0, w1;
      w0[0] = cvtpk(p[0][0], p[0][1]); w0[1] = cvtpk(p[0][2], p[0][3]);
      w0[2] = cvtpk(p[2][0], p[2][1]); w0[3] = cvtpk(p[2][2], p[2][3]);
      w1[0] = cvtpk(p[1][0], p[1][1]); w1[1] = cvtpk(p[1][2], p[1][3]);
      w1[2] = cvtpk(p[3][0], p[3][1]); w1[3] = cvtpk(p[3][2], p[3][3]);
      short8 pa0 = __builtin_bit_cast(short8, w0);
      short8 pa1 = __builtin_bit_cast(short8, w1);
      __builtin_amdgcn_s_setprio(1);
#pragma unroll
      for (int n = 0; n < 4; ++n) {
        acc[s][n] = __builtin_amdgcn_mfma_f32_16x16x32_bf16(pa0, vbf[n][0], acc[s][n], 0, 0, 0);
        acc[s][n] = __builtin_amdgcn_mfma_f32_16x16x32_bf16(pa1, vbf[n][1], acc[s][n], 0, 0, 0);
      }
      acc_l[s] = __builtin_amdgcn_mfma_f32_16x16x32_bf16(pa0, vones, acc_l[s], 0, 0, 0);
      acc_l[s] = __builtin_amdgcn_mfma_f32_16x16x32_bf16(pa1, vones, acc_l[s], 0, 0, 0);
      __builtin_amdgcn_s_setprio(0);
    }

    kb++;
    if (lastA) {   // tile A done: write out both subtiles, reset, switch to tile B
#pragma unroll
      for (int s = 0; s < 2; ++s) {
        float lf[4];
#pragma unroll
        for (int r = 0; r < 4; ++r) lf[r] = __shfl(acc_l[s][r], 16 * g);
#pragma unroll
        for (int r = 0; r < 4; ++r) {
          float inv = 1.0f / lf[r];
          int row = qrow + 16 * s + 4 * g + r;
          size_t obase = ((size_t)(b * Sq + row)) * Dq + h * 64;
#pragma unroll
          for (int n = 0; n < 4; ++n)
            Ctx[obase + 16 * n + l15] = f2bf(acc[s][n][r] * inv);
        }
      }
      qrow = tileB * 64 + 32 * w;
      tile = tileB;
      kb = 0;
#pragma unroll
      for (int s = 0; s < 2; ++s) {
#pragma unroll
        for (int hh = 0; hh < 2; ++hh)
          qf[s][hh] = *reinterpret_cast<const short8*>(&Qh[(size_t)(qrow + 16 * s + l15) * 64 + 32 * hh + 8 * g]);
#pragma unroll
        for (int n = 0; n < 4; ++n) acc[s][n] = f32x4{};
        acc_l[s] = f32x4{};
      }
    }

    __syncthreads();
    cur ^= 1;
  }

  {   // tile B epilogue
#pragma unroll
    for (int s = 0; s < 2; ++s) {
      float lf[4];
#pragma unroll
      for (int r = 0; r < 4; ++r) lf[r] = __shfl(acc_l[s][r], 16 * g);
#pragma unroll
      for (int r = 0; r < 4; ++r) {
        float inv = 1.0f / lf[r];
        int row = qrow + 16 * s + 4 * g + r;
        size_t obase = ((size_t)(b * Sq + row)) * Dq + h * 64;
#pragma unroll
        for (int n = 0; n < 4; ++n)
          Ctx[obase + 16 * n + l15] = f2bf(acc[s][n][r] * inv);
      }
    }
  }
}

extern "C" void kernel_launch(void* const* d_in, const int* in_sizes, int n_in,
                              void* d_out, int out_size, void* d_ws, size_t ws_size,
                              hipStream_t stream) {
  const float* X  = (const float*)d_in[0];   // [B,S,D] fp32
  const float* Wa = (const float*)d_in[1];   // [D,3D]
  const float* Ba = (const float*)d_in[2];   // [3D]
  const float* Wp = (const float*)d_in[3];   // [D,D]
  const float* Bp = (const float*)d_in[4];   // [D]
  float* Out = (float*)d_out;                // [B,S,D] fp32

  u16* ws  = (u16*)d_ws;
  u16* Xb  = ws;                                 // 8192*1024
  u16* WaT = Xb  + (size_t)BSq * Dq;             // 3072*1024
  u16* WpT = WaT + (size_t)3 * Dq * Dq;          // 1024*1024
  u16* Qb  = WpT + (size_t)Dq * Dq;              // 64*2048*64
  u16* Kb  = Qb  + (size_t)Bq * Hq * Sq * HDq;
  u16* Vt  = Kb  + (size_t)Bq * Hq * Sq * HDq;
  u16* Ctx = Vt  + (size_t)Bq * Hq * Sq * HDq;   // 8192*1024

  // 1) convert X to bf16 (8 floats/thread)
  cvt_kernel<<<(BSq * Dq / 8 + 255) / 256, 256, 0, stream>>>(X, Xb, BSq * Dq / 8);
  // 2) transpose+convert weights: W[K][N] -> WT[N][K] bf16
  transpose_cvt<<<dim3(3 * Dq / 32, Dq / 32), dim3(32, 8), 0, stream>>>(Wa, WaT, Dq, 3 * Dq);
  transpose_cvt<<<dim3(Dq / 32, Dq / 32), dim3(32, 8), 0, stream>>>(Wp, WpT, Dq, Dq);
  // 3) QKV GEMM (M=8192, N=3072, K=1024, BK=64) with Q/K/V scatter epilogue
  gemm_bt<0><<<dim3(3 * Dq / 128, BSq / 128), 256, 0, stream>>>(Xb, WaT, Ba, Qb, Kb, Vt, nullptr, Dq);
  // 4) causal flash attention -> Ctx (XCD-locality remap, paired tiles, 2-wave blocks)
  attn_kernel<<<dim3(16, Bq * Hq), 128, 0, stream>>>(Qb, Kb, Vt, Ctx);
  // 5) output projection (M=8192, N=1024, K=1024, BK=64) -> fp32 out
  gemm_bt<1><<<dim3(Dq / 128, BSq / 128), 256, 0, stream>>>(Ctx, WpT, Bp, nullptr, nullptr, nullptr, Out, Dq);
}

// Round 22
// 172.167 us; speedup vs baseline: 1.1420x; 1.0241x over previous
//
#include <hip/hip_runtime.h>

typedef unsigned short u16;
typedef __attribute__((ext_vector_type(8))) short short8;
typedef __attribute__((ext_vector_type(4))) float f32x4;
typedef __attribute__((ext_vector_type(4))) unsigned u32x4;

// Problem dims
#define Bq 4
#define Sq 2048
#define Dq 1024
#define Hq 16
#define HDq 64
#define BSq 8192   // B*S

// Q pre-scale: 1/sqrt(64) * log2(e)  (softmax done in exp2 domain)
#define QSCALE 0.18033688011112042f

__device__ __forceinline__ u16 f2bf(float f) {
  unsigned u = __builtin_bit_cast(unsigned, f);
  unsigned r = u + 0x7fffu + ((u >> 16) & 1u);
  return (u16)(r >> 16);
}

// pack two floats -> (bf16(a) | bf16(b)<<16)
__device__ __forceinline__ unsigned pk2(float a, float b) {
  unsigned ua = __builtin_bit_cast(unsigned, a) + 0x8000u;
  unsigned ub = __builtin_bit_cast(unsigned, b) + 0x8000u;
  return __builtin_amdgcn_perm(ub, ua, 0x07060302u);
}

// single-instruction pack: dst = {lo: bf16(a), hi: bf16(b)}
__device__ __forceinline__ unsigned cvtpk(float a, float b) {
  unsigned r;
  asm("v_cvt_pk_bf16_f32 %0, %1, %2" : "=v"(r) : "v"(a), "v"(b));
  return r;
}

// async global->LDS, 16B per lane (dest = wave-uniform base + lane*16)
__device__ __forceinline__ void gl_lds16(const u16* g, u16* l) {
  __builtin_amdgcn_global_load_lds((const __attribute__((address_space(1))) unsigned int*)g,
                                   (__attribute__((address_space(3))) unsigned int*)l, 16, 0, 0);
}

// k-permutation for V^T storage: kk = 16m + 4g + r -> s' = 32(m&1) + 8g + 4(m>>1) + r
__device__ __forceinline__ int kperm(int kk) {
  return ((kk & 0x10) << 1) | ((kk & 0x0C) << 1) | ((kk & 0x20) >> 3) | (kk & 3);
}

// ---------------- fused prologue: convert X + transpose both weight matrices ----------
// blocks [0,4096): X fp32 -> bf16 (8 floats/thread)
// blocks [4096,7168): Wa [1024][3072] -> WaT [3072][1024] (32x32 tiles)
// blocks [7168,8192): Wp [1024][1024] -> WpT [1024][1024]
__global__ __launch_bounds__(256)
void prologue_kernel(const float* __restrict__ X, u16* __restrict__ Xb,
                     const float* __restrict__ Wa, u16* __restrict__ WaT,
                     const float* __restrict__ Wp, u16* __restrict__ WpT) {
  __shared__ float tile[32][33];
  int bid = blockIdx.x;
  int tid = threadIdx.x;
  if (bid < 4096) {                    // X convert (block-uniform branch; no barrier)
    int i = bid * 256 + tid;
    float4 v0 = reinterpret_cast<const float4*>(X)[2 * i];
    float4 v1 = reinterpret_cast<const float4*>(X)[2 * i + 1];
    u32x4 o;
    o[0] = pk2(v0.x, v0.y); o[1] = pk2(v0.z, v0.w);
    o[2] = pk2(v1.x, v1.y); o[3] = pk2(v1.z, v1.w);
    reinterpret_cast<u32x4*>(Xb)[i] = o;
    return;
  }
  const float* in; u16* out; int C, t;
  if (bid < 7168) { t = bid - 4096; in = Wa; out = WaT; C = 3072; }
  else            { t = bid - 7168; in = Wp; out = WpT; C = 1024; }
  int ntx = C >> 5;
  int c0 = (t % ntx) * 32, r0 = (t / ntx) * 32;
  int tx = tid & 31, ty = tid >> 5;
  for (int i = ty; i < 32; i += 8)
    tile[i][tx] = in[(size_t)(r0 + i) * C + c0 + tx];
  __syncthreads();
  for (int i = ty; i < 32; i += 8)
    out[(size_t)(c0 + i) * 1024 + r0 + tx] = f2bf(tile[tx][i]);
}

// ---------------- bf16 GEMM: C[M,N] = A[M,K] * Bt[N,K]^T  (+bias) ----------------
// 128^2 tile, 4 waves, BK=64, single-buffered m97-style 2-barrier loop.
// (round-15 proven config: 16 ds_read_b128 feed 32 MFMA per wave per K-step)
// EPI 0: QKV epilogue; EPI 1: proj -> fp32 Out
template<int EPI>
__global__ __launch_bounds__(256)
void gemm_bt(const u16* __restrict__ A, const u16* __restrict__ Bt,
             const float* __restrict__ bias,
             u16* __restrict__ Qb, u16* __restrict__ Kb, u16* __restrict__ Vt,
             float* __restrict__ Out, int Kdim) {
  __shared__ __align__(16) u16 As[128 * 64];   // 16KB
  __shared__ __align__(16) u16 Bs[128 * 64];   // 16KB
  int tid = threadIdx.x;
  int lane = tid & 63;
  int wid = tid >> 6;
  int wr = wid >> 1, wc = wid & 1;       // 2x2 waves; each computes 64x64
  constexpr int NX = (EPI == 0) ? 24 : 8;        // N tiles
  constexpr int NWG = NX * 64;                   // both % 8 == 0
  int orig = (int)blockIdx.x + NX * (int)blockIdx.y;
  int swz = (orig & 7) * (NWG >> 3) + (orig >> 3);
  int m0 = (swz / NX) * 128, n0 = (swz % NX) * 128;
  int l15 = lane & 15, g = lane >> 4;
  f32x4 acc[4][4] = {};

  // staging map: f = i*256+tid (i=0..3); row = f>>3, slot = f&7;
  // LDS[row][slot*8..] holds global chunk (slot ^ (row&7)) -> linear dest f*16B
  const u16* aP[4];
  const u16* bP[4];
#pragma unroll
  for (int i = 0; i < 4; ++i) {
    int f = i * 256 + tid;
    int row = f >> 3, slot = f & 7;
    int src = ((slot ^ (row & 7)) << 3);
    aP[i] = &A[(size_t)(m0 + row) * Kdim + src];
    bP[i] = &Bt[(size_t)(n0 + row) * Kdim + src];
  }

  int nk = Kdim >> 6;   // BK=64
  for (int t = 0; t < nk; ++t) {
    __syncthreads();    // previous step's frag reads complete
    int ko = t << 6;
#pragma unroll
    for (int i = 0; i < 4; ++i) {
      int f = i * 256 + tid;
      gl_lds16(aP[i] + ko, &As[f << 3]);
      gl_lds16(bP[i] + ko, &Bs[f << 3]);
    }
    __syncthreads();    // vmcnt drained -> tiles visible
#pragma unroll
    for (int ksub = 0; ksub < 2; ++ksub) {
      int sl = (((ksub << 2) | g) ^ (l15 & 7)) << 3;
      short8 af[4], bfr[4];
#pragma unroll
      for (int m = 0; m < 4; ++m)
        af[m] = *reinterpret_cast<const short8*>(&As[(wr * 64 + m * 16 + l15) * 64 + sl]);
#pragma unroll
      for (int n = 0; n < 4; ++n)
        bfr[n] = *reinterpret_cast<const short8*>(&Bs[(wc * 64 + n * 16 + l15) * 64 + sl]);
      __builtin_amdgcn_s_setprio(1);
#pragma unroll
      for (int m = 0; m < 4; ++m)
#pragma unroll
        for (int n = 0; n < 4; ++n)
          acc[m][n] = __builtin_amdgcn_mfma_f32_16x16x32_bf16(af[m], bfr[n], acc[m][n], 0, 0, 0);
      __builtin_amdgcn_s_setprio(0);
    }
  }

  int bb = (m0 + wr * 64) >> 11;        // batch (wave-uniform)
  int sb = (m0 + wr * 64) & 2047;       // seq base (64-aligned)

  if (EPI == 1) {
#pragma unroll
    for (int m = 0; m < 4; ++m)
#pragma unroll
      for (int n = 0; n < 4; ++n) {
        int gcol = n0 + wc * 64 + n * 16 + l15;
        float bv = bias[gcol];
#pragma unroll
        for (int r = 0; r < 4; ++r) {
          int grow = m0 + wr * 64 + m * 16 + g * 4 + r;
          Out[(size_t)grow * 1024 + gcol] = acc[m][n][r] + bv;
        }
      }
  } else if (n0 < 1024) {               // Q block (scaled)
#pragma unroll
    for (int n = 0; n < 4; ++n) {
      int col = n0 + wc * 64 + n * 16 + l15;
      int hh = col >> 6, d = col & 63;
      float bv = bias[col];
      u16* qb = &Qb[(((size_t)(bb * 16 + hh) * 2048 + sb) << 6) + d];
#pragma unroll
      for (int m = 0; m < 4; ++m)
#pragma unroll
        for (int r = 0; r < 4; ++r)
          qb[(size_t)(m * 16 + g * 4 + r) << 6] = f2bf((acc[m][n][r] + bv) * QSCALE);
    }
  } else if (n0 < 2048) {               // K block
#pragma unroll
    for (int n = 0; n < 4; ++n) {
      int col = n0 - 1024 + wc * 64 + n * 16 + l15;
      int hh = col >> 6, d = col & 63;
      float bv = bias[1024 + col];
      u16* kb = &Kb[(((size_t)(bb * 16 + hh) * 2048 + sb) << 6) + d];
#pragma unroll
      for (int m = 0; m < 4; ++m)
#pragma unroll
        for (int r = 0; r < 4; ++r)
          kb[(size_t)(m * 16 + g * 4 + r) << 6] = f2bf(acc[m][n][r] + bv);
    }
  } else {                              // V block: vectorized k-permuted transpose write
#pragma unroll
    for (int n = 0; n < 4; ++n) {
      int cc = n0 - 2048 + wc * 64 + n * 16 + l15;
      int hh = cc >> 6, d = cc & 63;
      float bv = bias[2048 + cc];
      u16* dst = &Vt[((size_t)(bb * 16 + hh) * 64 + d) * 2048 + sb];
      u32x4 lo, hi;
      lo[0] = pk2(acc[0][n][0] + bv, acc[0][n][1] + bv);
      lo[1] = pk2(acc[0][n][2] + bv, acc[0][n][3] + bv);
      lo[2] = pk2(acc[2][n][0] + bv, acc[2][n][1] + bv);
      lo[3] = pk2(acc[2][n][2] + bv, acc[2][n][3] + bv);
      hi[0] = pk2(acc[1][n][0] + bv, acc[1][n][1] + bv);
      hi[1] = pk2(acc[1][n][2] + bv, acc[1][n][3] + bv);
      hi[2] = pk2(acc[3][n][0] + bv, acc[3][n][1] + bv);
      hi[3] = pk2(acc[3][n][2] + bv, acc[3][n][3] + bv);
      *reinterpret_cast<u32x4*>(dst + g * 8) = lo;
      *reinterpret_cast<u32x4*>(dst + 32 + g * 8) = hi;
    }
  }
}

// ---------------- flash attention (causal), swapped-QK^T, LDS-staged K/V ----------------
// grid: (16, 64) = 1024 blocks, 128 threads (2 waves). XCD-aware remap: each XCD
// runs 16 consecutive same-bh blocks -> K/V panel (512KB) is L2-resident per XCD.
// Block does q-tile pair (31-bx, bx): uniform 33 iters. Wave owns 32 rows (2
// subtiles of 16) sharing each K/V read set. dbuf-2 LDS, 1 barrier/iter.
// FIXED-max softmax; ones-MFMA row-sum.  (round-19 proven config)
__global__ __launch_bounds__(128, 2)
void attn_kernel(const u16* __restrict__ Qb, const u16* __restrict__ Kb,
                 const u16* __restrict__ Vt, u16* __restrict__ Ctx) {
  __shared__ __align__(16) u16 lds[2][2][8][512];   // [dbuf][K|V][slot][1KB]
  int tid = threadIdx.x, lane = tid & 63, w = tid >> 6;   // w in {0,1}
  int l15 = lane & 15, g = lane >> 4;
  // XCD-aware remap (dispatch round-robins id%8 across XCDs):
  int id = (int)blockIdx.x + 16 * (int)blockIdx.y;
  int xcd = id & 7, slot = id >> 3;           // slot: 0..127 within XCD
  int bh = (xcd << 3) | (slot >> 4);          // 8 bh per XCD, 16 blocks each
  int bx = slot & 15;                         // tile-pair index within bh
  const u16* Qh = Qb + (size_t)bh * Sq * HDq;
  const u16* Kh = Kb + (size_t)bh * Sq * HDq;
  const u16* Vh = Vt + (size_t)bh * HDq * Sq;
  int b = bh >> 4, h = bh & 15;

  int tileA = 31 - bx, tileB = bx;
  int nkA = tileA + 1;
  int ntot = nkA + tileB + 1;   // == 33 for every block

  // wave w stages K slots {4w..4w+3} (k-rows 32w..32w+31) and V slots {4w..4w+3}
  const u16* ksrc = Kh + (size_t)(32 * w + l15) * 64 + 8 * g;
  const u16* vsrc = Vh + (size_t)(32 * w + l15) * Sq + 8 * g;
  const u16* kpre = ksrc + 4096;   // next prefetch source (kb=1)
  const u16* vpre = vsrc + 64;

  int tile = tileA;
  int qrow = tileA * 64 + 32 * w;   // wave's rows: [qrow, qrow+32)

  short8 qf[2][2];
#pragma unroll
  for (int s = 0; s < 2; ++s)
#pragma unroll
    for (int hh = 0; hh < 2; ++hh)
      qf[s][hh] = *reinterpret_cast<const short8*>(&Qh[(size_t)(qrow + 16 * s + l15) * 64 + 32 * hh + 8 * g]);

  // ones B-frag: output col 0 of PV-ones = row sum of P
  u16 onebits = (l15 == 0) ? (u16)0x3F80 : (u16)0;
  short8 vones;
#pragma unroll
  for (int i = 0; i < 8; ++i) vones[i] = (short)onebits;

  f32x4 acc[2][4] = {};
  f32x4 acc_l[2] = {};

  // prologue: stage iter 0 into buf 0 (wave w: K slots 4w..4w+3, V slots 4w..4w+3)
  gl_lds16(ksrc,         &lds[0][0][4 * w][0]);
  gl_lds16(ksrc + 32,    &lds[0][0][4 * w + 1][0]);
  gl_lds16(ksrc + 1024,  &lds[0][0][4 * w + 2][0]);
  gl_lds16(ksrc + 1056,  &lds[0][0][4 * w + 3][0]);
  gl_lds16(vsrc,         &lds[0][1][4 * w][0]);
  gl_lds16(vsrc + 32,    &lds[0][1][4 * w + 1][0]);
  gl_lds16(vsrc + 32768, &lds[0][1][4 * w + 2][0]);
  gl_lds16(vsrc + 32800, &lds[0][1][4 * w + 3][0]);
  __syncthreads();
  int cur = 0;
  int kb = 0;

#pragma unroll 1
  for (int it = 0; it < ntot; ++it) {
    bool lastA = (it == nkA - 1);
    int k0 = kb << 6;

    if (it + 1 < ntot) {   // prefetch next iteration (strength-reduced pointers)
      gl_lds16(kpre,         &lds[cur ^ 1][0][4 * w][0]);
      gl_lds16(kpre + 32,    &lds[cur ^ 1][0][4 * w + 1][0]);
      gl_lds16(kpre + 1024,  &lds[cur ^ 1][0][4 * w + 2][0]);
      gl_lds16(kpre + 1056,  &lds[cur ^ 1][0][4 * w + 3][0]);
      gl_lds16(vpre,         &lds[cur ^ 1][1][4 * w][0]);
      gl_lds16(vpre + 32,    &lds[cur ^ 1][1][4 * w + 1][0]);
      gl_lds16(vpre + 32768, &lds[cur ^ 1][1][4 * w + 2][0]);
      gl_lds16(vpre + 32800, &lds[cur ^ 1][1][4 * w + 3][0]);
      if (it == nkA - 2) { kpre = ksrc; vpre = vsrc; }   // wrap to tile-B's kb=0
      else               { kpre += 4096; vpre += 64; }
    }

    short8 kf[4][2], vbf[4][2];
#pragma unroll
    for (int j = 0; j < 4; ++j) {
      kf[j][0] = *reinterpret_cast<const short8*>(&lds[cur][0][2 * j][lane * 8]);
      kf[j][1] = *reinterpret_cast<const short8*>(&lds[cur][0][2 * j + 1][lane * 8]);
    }
#pragma unroll
    for (int n = 0; n < 4; ++n) {
      vbf[n][0] = *reinterpret_cast<const short8*>(&lds[cur][1][2 * n][lane * 8]);
      vbf[n][1] = *reinterpret_cast<const short8*>(&lds[cur][1][2 * n + 1][lane * 8]);
    }

#pragma unroll
    for (int s = 0; s < 2; ++s) {      // two 16-row subtiles share kf/vbf
      int q0s = qrow + 16 * s;

      f32x4 sj[4];
      __builtin_amdgcn_s_setprio(1);
#pragma unroll
      for (int j = 0; j < 4; ++j) {
        f32x4 z = {};
        z = __builtin_amdgcn_mfma_f32_16x16x32_bf16(kf[j][0], qf[s][0], z, 0, 0, 0);
        z = __builtin_amdgcn_mfma_f32_16x16x32_bf16(kf[j][1], qf[s][1], z, 0, 0, 0);
        sj[j] = z;
      }
      __builtin_amdgcn_s_setprio(0);

      if (kb == tile) {   // diagonal block: causal mask
        int q = q0s + l15;
#pragma unroll
        for (int j = 0; j < 4; ++j)
#pragma unroll
          for (int r = 0; r < 4; ++r)
            if (k0 + 16 * j + 4 * g + r > q) sj[j][r] = -1e30f;
      }

      // fixed-max softmax: P = exp2(s) directly (masked -> 0)
      float p[4][4];
#pragma unroll
      for (int j = 0; j < 4; ++j)
#pragma unroll
        for (int r = 0; r < 4; ++r)
          p[j][r] = exp2f(sj[j][r]);

      u32x4 w0, w1;
      w0[0] = cvtpk(p[0][0], p[0][1]); w0[1] = cvtpk(p[0][2], p[0][3]);
      w0[2] = cvtpk(p[2][0], p[2][1]); w0[3] = cvtpk(p[2][2], p[2][3]);
      w1[0] = cvtpk(p[1][0], p[1][1]); w1[1] = cvtpk(p[1][2], p[1][3]);
      w1[2] = cvtpk(p[3][0], p[3][1]); w1[3] = cvtpk(p[3][2], p[3][3]);
      short8 pa0 = __builtin_bit_cast(short8, w0);
      short8 pa1 = __builtin_bit_cast(short8, w1);
      __builtin_amdgcn_s_setprio(1);
#pragma unroll
      for (int n = 0; n < 4; ++n) {
        acc[s][n] = __builtin_amdgcn_mfma_f32_16x16x32_bf16(pa0, vbf[n][0], acc[s][n], 0, 0, 0);
        acc[s][n] = __builtin_amdgcn_mfma_f32_16x16x32_bf16(pa1, vbf[n][1], acc[s][n], 0, 0, 0);
      }
      acc_l[s] = __builtin_amdgcn_mfma_f32_16x16x32_bf16(pa0, vones, acc_l[s], 0, 0, 0);
      acc_l[s] = __builtin_amdgcn_mfma_f32_16x16x32_bf16(pa1, vones, acc_l[s], 0, 0, 0);
      __builtin_amdgcn_s_setprio(0);
    }

    kb++;
    if (lastA) {   // tile A done: write out both subtiles, reset, switch to tile B
#pragma unroll
      for (int s = 0; s < 2; ++s) {
        float lf[4];
#pragma unroll
        for (int r = 0; r < 4; ++r) lf[r] = __shfl(acc_l[s][r], 16 * g);
#pragma unroll
        for (int r = 0; r < 4; ++r) {
          float inv = 1.0f / lf[r];
          int row = qrow + 16 * s + 4 * g + r;
          size_t obase = ((size_t)(b * Sq + row)) * Dq + h * 64;
#pragma unroll
          for (int n = 0; n < 4; ++n)
            Ctx[obase + 16 * n + l15] = f2bf(acc[s][n][r] * inv);
        }
      }
      qrow = tileB * 64 + 32 * w;
      tile = tileB;
      kb = 0;
#pragma unroll
      for (int s = 0; s < 2; ++s) {
#pragma unroll
        for (int hh = 0; hh < 2; ++hh)
          qf[s][hh] = *reinterpret_cast<const short8*>(&Qh[(size_t)(qrow + 16 * s + l15) * 64 + 32 * hh + 8 * g]);
#pragma unroll
        for (int n = 0; n < 4; ++n) acc[s][n] = f32x4{};
        acc_l[s] = f32x4{};
      }
    }

    __syncthreads();
    cur ^= 1;
  }

  {   // tile B epilogue
#pragma unroll
    for (int s = 0; s < 2; ++s) {
      float lf[4];
#pragma unroll
      for (int r = 0; r < 4; ++r) lf[r] = __shfl(acc_l[s][r], 16 * g);
#pragma unroll
      for (int r = 0; r < 4; ++r) {
        float inv = 1.0f / lf[r];
        int row = qrow + 16 * s + 4 * g + r;
        size_t obase = ((size_t)(b * Sq + row)) * Dq + h * 64;
#pragma unroll
        for (int n = 0; n < 4; ++n)
          Ctx[obase + 16 * n + l15] = f2bf(acc[s][n][r] * inv);
      }
    }
  }
}

extern "C" void kernel_launch(void* const* d_in, const int* in_sizes, int n_in,
                              void* d_out, int out_size, void* d_ws, size_t ws_size,
                              hipStream_t stream) {
  const float* X  = (const float*)d_in[0];   // [B,S,D] fp32
  const float* Wa = (const float*)d_in[1];   // [D,3D]
  const float* Ba = (const float*)d_in[2];   // [3D]
  const float* Wp = (const float*)d_in[3];   // [D,D]
  const float* Bp = (const float*)d_in[4];   // [D]
  float* Out = (float*)d_out;                // [B,S,D] fp32

  u16* ws  = (u16*)d_ws;
  u16* Xb  = ws;                                 // 8192*1024
  u16* WaT = Xb  + (size_t)BSq * Dq;             // 3072*1024
  u16* WpT = WaT + (size_t)3 * Dq * Dq;          // 1024*1024
  u16* Qb  = WpT + (size_t)Dq * Dq;              // 64*2048*64
  u16* Kb  = Qb  + (size_t)Bq * Hq * Sq * HDq;
  u16* Vt  = Kb  + (size_t)Bq * Hq * Sq * HDq;
  u16* Ctx = Vt  + (size_t)Bq * Hq * Sq * HDq;   // 8192*1024

  // 1) fused prologue: X convert + Wa/Wp transpose-convert (one dispatch)
  prologue_kernel<<<8192, 256, 0, stream>>>(X, Xb, Wa, WaT, Wp, WpT);
  // 2) QKV GEMM (M=8192, N=3072, K=1024, BK=64) with Q/K/V scatter epilogue
  gemm_bt<0><<<dim3(3 * Dq / 128, BSq / 128), 256, 0, stream>>>(Xb, WaT, Ba, Qb, Kb, Vt, nullptr, Dq);
  // 3) causal flash attention -> Ctx (XCD-locality remap, paired tiles, 2-wave blocks)
  attn_kernel<<<dim3(16, Bq * Hq), 128, 0, stream>>>(Qb, Kb, Vt, Ctx);
  // 4) output projection (M=8192, N=1024, K=1024, BK=64) -> fp32 out
  gemm_bt<1><<<dim3(Dq / 128, BSq / 128), 256, 0, stream>>>(Ctx, WpT, Bp, nullptr, nullptr, nullptr, Out, Dq);
}